// Round 5
// baseline (575.118 us; speedup 1.0000x reference)
//
#include <hip/hip_runtime.h>
#include <math.h>

#define NU 100000
#define NI 50000
#define NT 150000      // NU + NI
#define D  64
#define NNZ_ 4000000
#define BATCH_ 4096
#define WDECAY 1e-4f

#define BROWS 2048                 // rows per bucket
#define NBKT 74                    // ceil(NT / BROWS)
#define BCAP 57344                 // bucket capacity (mean 54613, sigma ~234)
#define CURS 16                    // cursor stride (64B anti-contention pad)
#define EPB 16                     // edges per thread in binA
#define BATCH_E (256 * EPB)        // 4096 edges per block-batch
#define NBLK_A ((NNZ_ + BATCH_E - 1) / BATCH_E)   // 977

static __device__ __forceinline__ float bf2f(ushort u) {
    return __uint_as_float(((unsigned int)u) << 16);
}
static __device__ __forceinline__ ushort f2bf(float f) {
    unsigned int u = __float_as_uint(f);
    u += 0x7FFF + ((u >> 16) & 1);      // RTNE
    return (ushort)(u >> 16);
}

// ---- init: cur0 = bf16(concat(ue, ie)); zero loss scalars -------------------
__global__ void init_kernel(const float* __restrict__ ue, const float* __restrict__ ie,
                            ushort* __restrict__ cur0, float* __restrict__ scal) {
    int i = blockIdx.x * blockDim.x + threadIdx.x;
    const int total4 = NT * D / 4;
    if (i == 0) { scal[0] = 0.f; scal[1] = 0.f; }
    if (i >= total4) return;
    const int usz4 = NU * D / 4;
    float4 v = (i < usz4) ? ((const float4*)ue)[i] : ((const float4*)ie)[i - usz4];
    ushort4 o;
    o.x = f2bf(v.x); o.y = f2bf(v.y); o.z = f2bf(v.z); o.w = f2bf(v.w);
    ((ushort4*)cur0)[i] = o;
}

// ---- binA: block-aggregated bucket append (runs are block-private) ----------
__global__ void binA_kernel(const int* __restrict__ rows, const int* __restrict__ cols,
                            const float* __restrict__ vals,
                            int* __restrict__ cursor, int2* __restrict__ binned) {
    __shared__ int cnt[NBKT];
    __shared__ int gbase[NBKT];
    int tid = threadIdx.x;
    int b0 = blockIdx.x * BATCH_E;
    if (tid < NBKT) cnt[tid] = 0;
    __syncthreads();
    // phase 1: rank within (batch, bucket).  pack = rl | (bkt<<11) | (rank<<18)
    int pack[EPB];
    #pragma unroll
    for (int k = 0; k < EPB; ++k) {
        int i = b0 + k * 256 + tid;
        if (i < NNZ_) {
            int r = rows[i];
            int b = r >> 11;
            int rk = atomicAdd(&cnt[b], 1);
            pack[k] = (r & (BROWS - 1)) | (b << 11) | (rk << 18);
        } else pack[k] = -1;
    }
    __syncthreads();
    // phase 2: reserve one contiguous global run per bucket
    if (tid < NBKT) {
        int c = cnt[tid];
        gbase[tid] = c ? atomicAdd(&cursor[tid * CURS], c) : 0;
    }
    __syncthreads();
    // phase 3: write
    #pragma unroll
    for (int k = 0; k < EPB; ++k) {
        int pk = pack[k];
        if (pk >= 0) {
            int i  = b0 + k * 256 + tid;
            int rl = pk & (BROWS - 1);
            int b  = (pk >> 11) & 127;
            int rk = pk >> 18;
            int2 e;
            e.x = rl | (cols[i] << 11);
            e.y = __float_as_int(vals[i]);
            binned[(size_t)b * BCAP + gbase[b] + rk] = e;
        }
    }
}

// ---- bucket-base scan (74 buckets, single block) ----------------------------
__global__ void bscan_kernel(const int* __restrict__ cursor, int* __restrict__ bbase,
                             int* __restrict__ rowptr) {
    __shared__ int s[128];
    int t = threadIdx.x;
    int v = (t < NBKT) ? cursor[t * CURS] : 0;
    s[t] = v; __syncthreads();
    for (int off = 1; off < 128; off <<= 1) {
        int x = (t >= off) ? s[t - off] : 0;
        __syncthreads();
        s[t] += x;
        __syncthreads();
    }
    if (t < NBKT) bbase[t] = s[t] - v;
    if (t == 0) rowptr[NT] = NNZ_;
}

// ---- binB: per-bucket LDS counting sort (2048 rows) -> CSR ------------------
__global__ void binB_kernel(const int2* __restrict__ binned, const int* __restrict__ cursor,
                            const int* __restrict__ bbase,
                            int2* __restrict__ colval, int* __restrict__ rowptr) {
    __shared__ int cnt[BROWS];
    __shared__ int sc[1024];
    __shared__ int offs[BROWS];
    int b   = blockIdx.x;
    int tid = threadIdx.x;
    int cb  = cursor[b * CURS];
    int base = bbase[b];
    const int2* eb = binned + (size_t)b * BCAP;
    cnt[tid] = 0; cnt[tid + 1024] = 0;
    __syncthreads();
    for (int i = tid; i < cb; i += 1024)
        atomicAdd(&cnt[eb[i].x & (BROWS - 1)], 1);
    __syncthreads();
    int v0 = cnt[2 * tid], v1 = cnt[2 * tid + 1];
    sc[tid] = v0 + v1;
    __syncthreads();
    for (int off = 1; off < 1024; off <<= 1) {
        int x = (tid >= off) ? sc[tid - off] : 0;
        __syncthreads();
        sc[tid] += x;
        __syncthreads();
    }
    int pbase = sc[tid] - (v0 + v1);
    offs[2 * tid]     = pbase;
    offs[2 * tid + 1] = pbase + v0;
    int row0 = b * BROWS + 2 * tid;
    if (row0 < NT)     rowptr[row0]     = base + pbase;
    if (row0 + 1 < NT) rowptr[row0 + 1] = base + pbase + v0;
    __syncthreads();
    for (int i = tid; i < cb; i += 1024) {
        int2 e = eb[i];
        int rl = e.x & (BROWS - 1);
        int p  = base + atomicAdd(&offs[rl], 1);
        int2 cv; cv.x = e.x >> 11; cv.y = e.y;
        colval[p] = cv;
    }
}

// ---- quad-ILP row core: 4 edges in flight, ushort4 gathers ------------------
static __device__ __forceinline__ void row_core(const int* __restrict__ rowptr,
                                                const int2* __restrict__ colval,
                                                const ushort* __restrict__ x,
                                                int r, int lane,
                                                float& s0, float& s1, float& s2, float& s3) {
    int q  = lane >> 4;
    int ql = lane & 15;
    int beg = rowptr[r], end = rowptr[r + 1];
    s0 = s1 = s2 = s3 = 0.f;
    for (int base = beg; base < end; base += 64) {
        int m = end - base; if (m > 64) m = 64;
        int idx = base + lane; if (idx > NNZ_ - 1) idx = NNZ_ - 1;
        int2 cv = colval[idx];
        int nq = (m + 3) >> 2;
        #pragma unroll 8
        for (int j = 0; j < nq; ++j) {
            int e = 4 * j + q;
            int   c = __shfl(cv.x, e);
            float v = __int_as_float(__shfl(cv.y, e));
            if (e >= m) v = 0.f;
            ushort4 xv = *(const ushort4*)(x + (size_t)c * D + ql * 4);
            s0 += v * bf2f(xv.x); s1 += v * bf2f(xv.y);
            s2 += v * bf2f(xv.z); s3 += v * bf2f(xv.w);
        }
    }
    s0 += __shfl_xor(s0, 16); s0 += __shfl_xor(s0, 32);
    s1 += __shfl_xor(s1, 16); s1 += __shfl_xor(s1, 32);
    s2 += __shfl_xor(s2, 16); s2 += __shfl_xor(s2, 32);
    s3 += __shfl_xor(s3, 16); s3 += __shfl_xor(s3, 32);
}

// ---- SpMM (CSR gather): one wave per row ------------------------------------
__global__ void spmm_kernel(const int* __restrict__ rowptr, const int2* __restrict__ colval,
                            const ushort* __restrict__ x, ushort* __restrict__ y) {
    int gtid = blockIdx.x * blockDim.x + threadIdx.x;
    int r    = gtid >> 6;
    int lane = threadIdx.x & 63;
    if (r >= NT) return;
    float s0, s1, s2, s3;
    row_core(rowptr, colval, x, r, lane, s0, s1, s2, s3);
    if ((lane >> 4) == 0) {
        int ql = lane & 15;
        ushort4 o;
        o.x = f2bf(s0); o.y = f2bf(s1); o.z = f2bf(s2); o.w = f2bf(s3);
        *(ushort4*)(y + (size_t)r * D + ql * 4) = o;
    }
}

// ---- walk: layer-3 rows needed by the loss, one wave per (batch,role) -------
__global__ void walk_kernel(const ushort* __restrict__ o2,
                            const int* __restrict__ rowptr, const int2* __restrict__ colval,
                            const int* __restrict__ users, const int* __restrict__ pos,
                            const int* __restrict__ neg, float* __restrict__ wbuf) {
    int gtid = blockIdx.x * blockDim.x + threadIdx.x;
    int task = gtid >> 6;
    int lane = threadIdx.x & 63;
    if (task >= 3 * BATCH_) return;
    int role = task >> 12;                // BATCH_ = 4096
    int b    = task & (BATCH_ - 1);
    int r = (role == 0) ? users[b] : (role == 1) ? NU + pos[b] : NU + neg[b];
    float s0, s1, s2, s3;
    row_core(rowptr, colval, o2, r, lane, s0, s1, s2, s3);
    if ((lane >> 4) == 0) {
        int ql = lane & 15;
        float4 o; o.x = s0; o.y = s1; o.z = s2; o.w = s3;
        *(float4*)(wbuf + (size_t)task * D + ql * 4) = o;
    }
}

// ---- loss: light = (e0 + o1 + o2 + wbuf)/4 ----------------------------------
__global__ void loss_kernel(const float* __restrict__ ue, const float* __restrict__ ie,
                            const ushort* __restrict__ o1, const ushort* __restrict__ o2,
                            const float* __restrict__ wbuf,
                            const int* __restrict__ users, const int* __restrict__ pos,
                            const int* __restrict__ neg, float* __restrict__ scal) {
    int gtid = blockIdx.x * blockDim.x + threadIdx.x;
    int wid  = gtid >> 6;
    int lane = threadIdx.x & 63;
    int nw   = (gridDim.x * blockDim.x) >> 6;
    for (int b = wid; b < BATCH_; b += nw) {
        int u = users[b], p = pos[b], n = neg[b];
        int ru = u, rp = NU + p, rn = NU + n;
        float uo = ue[(size_t)u * D + lane];
        float po = ie[(size_t)p * D + lane];
        float no = ie[(size_t)n * D + lane];
        float lu = uo + bf2f(o1[(size_t)ru * D + lane]) + bf2f(o2[(size_t)ru * D + lane])
                      + wbuf[(size_t)(0 * BATCH_ + b) * D + lane];
        float lp = po + bf2f(o1[(size_t)rp * D + lane]) + bf2f(o2[(size_t)rp * D + lane])
                      + wbuf[(size_t)(1 * BATCH_ + b) * D + lane];
        float ln_ = no + bf2f(o1[(size_t)rn * D + lane]) + bf2f(o2[(size_t)rn * D + lane])
                      + wbuf[(size_t)(2 * BATCH_ + b) * D + lane];
        float ps = lu * lp;
        float ns = lu * ln_;
        float rg = uo * uo + po * po + no * no;
        #pragma unroll
        for (int off = 32; off > 0; off >>= 1) {
            ps += __shfl_down(ps, off);
            ns += __shfl_down(ns, off);
            rg += __shfl_down(rg, off);
        }
        if (lane == 0) {
            float diff = (ns - ps) * (1.0f / 16.0f);
            float sp = diff > 0.f ? diff + log1pf(expf(-diff)) : log1pf(expf(diff));
            atomicAdd(&scal[0], sp);
            atomicAdd(&scal[1], rg);
        }
    }
}

__global__ void finalize_kernel(const float* __restrict__ scal, float* __restrict__ out) {
    out[0] = scal[0] / (float)BATCH_ + WDECAY * 0.5f * scal[1] / (float)BATCH_;
}

extern "C" void kernel_launch(void* const* d_in, const int* in_sizes, int n_in,
                              void* d_out, int out_size, void* d_ws, size_t ws_size,
                              hipStream_t stream) {
    const float* user_emb = (const float*)d_in[0];
    const float* item_emb = (const float*)d_in[1];
    const int*   g_rows   = (const int*)d_in[2];
    const int*   g_cols   = (const int*)d_in[3];
    const float* g_vals   = (const float*)d_in[4];
    const int*   users    = (const int*)d_in[5];
    const int*   pos      = (const int*)d_in[6];
    const int*   neg      = (const int*)d_in[7];
    float* out = (float*)d_out;

    const size_t TABH = (size_t)NT * D * 2;            // 19.2 MB bf16 table
    char* ws = (char*)d_ws;
    ushort* cur0   = (ushort*)(ws);
    ushort* o1     = (ushort*)(ws + TABH);
    ushort* o2     = (ushort*)(ws + 2 * TABH);
    int2*   colval = (int2*)  (ws + 3 * TABH);                       // 32 MB
    int2*   binned = (int2*)  (ws + 3 * TABH + (size_t)NNZ_ * 8);    // 33.9 MB
    char*   p      = ws + 3 * TABH + (size_t)NNZ_ * 8 + (size_t)NBKT * BCAP * 8;
    int*    rowptr = (int*)(p);      p += ((size_t)(NT + 1) * 4 + 255) / 256 * 256;
    int*    cursor = (int*)(p);      p += (size_t)NBKT * CURS * 4;
    int*    bbase  = (int*)(p);      p += 1024;
    float*  scal   = (float*)(p);    p += 256;
    float*  wbuf   = (float*)(p);    // 3*BATCH_*64*4 = 3.1 MB

    hipMemsetAsync(cursor, 0, (size_t)NBKT * CURS * 4, stream);
    init_kernel<<<(NT * D / 4 + 255) / 256, 256, 0, stream>>>(user_emb, item_emb, cur0, scal);

    binA_kernel<<<NBLK_A, 256, 0, stream>>>(g_rows, g_cols, g_vals, cursor, binned);
    bscan_kernel<<<1, 128, 0, stream>>>(cursor, bbase, rowptr);
    binB_kernel<<<NBKT, 1024, 0, stream>>>(binned, cursor, bbase, colval, rowptr);

    const int SPMM_BLOCKS = (NT + 3) / 4;   // one wave per row, 4 waves/block
    spmm_kernel<<<SPMM_BLOCKS, 256, 0, stream>>>(rowptr, colval, cur0, o1);
    spmm_kernel<<<SPMM_BLOCKS, 256, 0, stream>>>(rowptr, colval, o1, o2);

    walk_kernel<<<(3 * BATCH_ + 3) / 4, 256, 0, stream>>>(o2, rowptr, colval,
                                                          users, pos, neg, wbuf);
    loss_kernel<<<256, 256, 0, stream>>>(user_emb, item_emb, o1, o2, wbuf,
                                         users, pos, neg, scal);
    finalize_kernel<<<1, 1, 0, stream>>>(scal, out);
}

// Round 6
// 469.476 us; speedup vs baseline: 1.2250x; 1.2250x over previous
//
#include <hip/hip_runtime.h>
#include <math.h>

#define NU 100000
#define NI 50000
#define NT 150000      // NU + NI
#define D  64
#define NNZ_ 4000000
#define BATCH_ 4096
#define WDECAY 1e-4f

#define BROWS 2048                 // rows per bucket
#define NBKT 74                    // ceil(NT / BROWS)
#define BCAP 57344                 // bucket capacity (mean 54613, sigma ~234)
#define CURS 16                    // cursor stride (64B anti-contention pad)
#define EPB 16                     // edges per thread in binA
#define BATCH_E (256 * EPB)        // 4096 edges per block-batch
#define NBLK_A ((NNZ_ + BATCH_E - 1) / BATCH_E)   // 977
#define NBLO 512                   // loss blocks (partials, no atomics)

static __device__ __forceinline__ float bf2f(ushort u) {
    return __uint_as_float(((unsigned int)u) << 16);
}
static __device__ __forceinline__ ushort f2bf(float f) {
    unsigned int u = __float_as_uint(f);
    u += 0x7FFF + ((u >> 16) & 1);      // RTNE
    return (ushort)(u >> 16);
}

// ---- init: cur0 = bf16(concat(ue, ie)) --------------------------------------
__global__ void init_kernel(const float* __restrict__ ue, const float* __restrict__ ie,
                            ushort* __restrict__ cur0) {
    int i = blockIdx.x * blockDim.x + threadIdx.x;
    const int total4 = NT * D / 4;
    if (i >= total4) return;
    const int usz4 = NU * D / 4;
    float4 v = (i < usz4) ? ((const float4*)ue)[i] : ((const float4*)ie)[i - usz4];
    ushort4 o;
    o.x = f2bf(v.x); o.y = f2bf(v.y); o.z = f2bf(v.z); o.w = f2bf(v.w);
    ((ushort4*)cur0)[i] = o;
}

// ---- binA: block-aggregated bucket append (runs are block-private) ----------
__global__ void binA_kernel(const int* __restrict__ rows, const int* __restrict__ cols,
                            const float* __restrict__ vals,
                            int* __restrict__ cursor, int2* __restrict__ binned) {
    __shared__ int cnt[NBKT];
    __shared__ int gbase[NBKT];
    int tid = threadIdx.x;
    int b0 = blockIdx.x * BATCH_E;
    if (tid < NBKT) cnt[tid] = 0;
    __syncthreads();
    int pack[EPB];
    #pragma unroll
    for (int k = 0; k < EPB; ++k) {
        int i = b0 + k * 256 + tid;
        if (i < NNZ_) {
            int r = rows[i];
            int b = r >> 11;
            int rk = atomicAdd(&cnt[b], 1);
            pack[k] = (r & (BROWS - 1)) | (b << 11) | (rk << 18);
        } else pack[k] = -1;
    }
    __syncthreads();
    if (tid < NBKT) {
        int c = cnt[tid];
        gbase[tid] = c ? atomicAdd(&cursor[tid * CURS], c) : 0;
    }
    __syncthreads();
    #pragma unroll
    for (int k = 0; k < EPB; ++k) {
        int pk = pack[k];
        if (pk >= 0) {
            int i  = b0 + k * 256 + tid;
            int rl = pk & (BROWS - 1);
            int b  = (pk >> 11) & 127;
            int rk = pk >> 18;
            int2 e;
            e.x = rl | (cols[i] << 11);
            e.y = __float_as_int(vals[i]);
            binned[(size_t)b * BCAP + gbase[b] + rk] = e;
        }
    }
}

// ---- bucket-base scan (74 buckets, single block) ----------------------------
__global__ void bscan_kernel(const int* __restrict__ cursor, int* __restrict__ bbase,
                             int* __restrict__ rowptr) {
    __shared__ int s[128];
    int t = threadIdx.x;
    int v = (t < NBKT) ? cursor[t * CURS] : 0;
    s[t] = v; __syncthreads();
    for (int off = 1; off < 128; off <<= 1) {
        int x = (t >= off) ? s[t - off] : 0;
        __syncthreads();
        s[t] += x;
        __syncthreads();
    }
    if (t < NBKT) bbase[t] = s[t] - v;
    if (t == 0) rowptr[NT] = NNZ_;
}

// ---- binB: per-bucket LDS counting sort (2048 rows) -> CSR ------------------
__global__ void binB_kernel(const int2* __restrict__ binned, const int* __restrict__ cursor,
                            const int* __restrict__ bbase,
                            int2* __restrict__ colval, int* __restrict__ rowptr) {
    __shared__ int cnt[BROWS];
    __shared__ int sc[1024];
    __shared__ int offs[BROWS];
    int b   = blockIdx.x;
    int tid = threadIdx.x;
    int cb  = cursor[b * CURS];
    int base = bbase[b];
    const int2* eb = binned + (size_t)b * BCAP;
    cnt[tid] = 0; cnt[tid + 1024] = 0;
    __syncthreads();
    for (int i = tid; i < cb; i += 1024)
        atomicAdd(&cnt[eb[i].x & (BROWS - 1)], 1);
    __syncthreads();
    int v0 = cnt[2 * tid], v1 = cnt[2 * tid + 1];
    sc[tid] = v0 + v1;
    __syncthreads();
    for (int off = 1; off < 1024; off <<= 1) {
        int x = (tid >= off) ? sc[tid - off] : 0;
        __syncthreads();
        sc[tid] += x;
        __syncthreads();
    }
    int pbase = sc[tid] - (v0 + v1);
    offs[2 * tid]     = pbase;
    offs[2 * tid + 1] = pbase + v0;
    int row0 = b * BROWS + 2 * tid;
    if (row0 < NT)     rowptr[row0]     = base + pbase;
    if (row0 + 1 < NT) rowptr[row0 + 1] = base + pbase + v0;
    __syncthreads();
    for (int i = tid; i < cb; i += 1024) {
        int2 e = eb[i];
        int rl = e.x & (BROWS - 1);
        int p  = base + atomicAdd(&offs[rl], 1);
        int2 cv; cv.x = e.x >> 11; cv.y = e.y;
        colval[p] = cv;
    }
}

// ---- quad-ILP row core: 4 edges in flight, ushort4 gathers ------------------
static __device__ __forceinline__ void row_core(const int* __restrict__ rowptr,
                                                const int2* __restrict__ colval,
                                                const ushort* __restrict__ x,
                                                int r, int lane,
                                                float& s0, float& s1, float& s2, float& s3) {
    int q  = lane >> 4;
    int ql = lane & 15;
    int beg = rowptr[r], end = rowptr[r + 1];
    s0 = s1 = s2 = s3 = 0.f;
    for (int base = beg; base < end; base += 64) {
        int m = end - base; if (m > 64) m = 64;
        int idx = base + lane; if (idx > NNZ_ - 1) idx = NNZ_ - 1;
        int2 cv = colval[idx];
        int nq = (m + 3) >> 2;
        #pragma unroll 8
        for (int j = 0; j < nq; ++j) {
            int e = 4 * j + q;
            int   c = __shfl(cv.x, e);
            float v = __int_as_float(__shfl(cv.y, e));
            if (e >= m) v = 0.f;
            ushort4 xv = *(const ushort4*)(x + (size_t)c * D + ql * 4);
            s0 += v * bf2f(xv.x); s1 += v * bf2f(xv.y);
            s2 += v * bf2f(xv.z); s3 += v * bf2f(xv.w);
        }
    }
    s0 += __shfl_xor(s0, 16); s0 += __shfl_xor(s0, 32);
    s1 += __shfl_xor(s1, 16); s1 += __shfl_xor(s1, 32);
    s2 += __shfl_xor(s2, 16); s2 += __shfl_xor(s2, 32);
    s3 += __shfl_xor(s3, 16); s3 += __shfl_xor(s3, 32);
}

// ---- SpMM (CSR gather): one wave per row ------------------------------------
__global__ void spmm_kernel(const int* __restrict__ rowptr, const int2* __restrict__ colval,
                            const ushort* __restrict__ x, ushort* __restrict__ y) {
    int gtid = blockIdx.x * blockDim.x + threadIdx.x;
    int r    = gtid >> 6;
    int lane = threadIdx.x & 63;
    if (r >= NT) return;
    float s0, s1, s2, s3;
    row_core(rowptr, colval, x, r, lane, s0, s1, s2, s3);
    if ((lane >> 4) == 0) {
        int ql = lane & 15;
        ushort4 o;
        o.x = f2bf(s0); o.y = f2bf(s1); o.z = f2bf(s2); o.w = f2bf(s3);
        *(ushort4*)(y + (size_t)r * D + ql * 4) = o;
    }
}

// ---- walk: layer-3 rows needed by the loss, one wave per (batch,role) -------
__global__ void walk_kernel(const ushort* __restrict__ o2,
                            const int* __restrict__ rowptr, const int2* __restrict__ colval,
                            const int* __restrict__ users, const int* __restrict__ pos,
                            const int* __restrict__ neg, float* __restrict__ wbuf) {
    int gtid = blockIdx.x * blockDim.x + threadIdx.x;
    int task = gtid >> 6;
    int lane = threadIdx.x & 63;
    if (task >= 3 * BATCH_) return;
    int role = task >> 12;                // BATCH_ = 4096
    int b    = task & (BATCH_ - 1);
    int r = (role == 0) ? users[b] : (role == 1) ? NU + pos[b] : NU + neg[b];
    float s0, s1, s2, s3;
    row_core(rowptr, colval, o2, r, lane, s0, s1, s2, s3);
    if ((lane >> 4) == 0) {
        int ql = lane & 15;
        float4 o; o.x = s0; o.y = s1; o.z = s2; o.w = s3;
        *(float4*)(wbuf + (size_t)task * D + ql * 4) = o;
    }
}

// ---- loss: per-block partials (no global atomics) ---------------------------
__global__ void loss_kernel(const float* __restrict__ ue, const float* __restrict__ ie,
                            const ushort* __restrict__ o1, const ushort* __restrict__ o2,
                            const float* __restrict__ wbuf,
                            const int* __restrict__ users, const int* __restrict__ pos,
                            const int* __restrict__ neg, float* __restrict__ pbuf) {
    __shared__ float ssp[4];
    __shared__ float srg[4];
    int tid  = threadIdx.x;
    int wv   = tid >> 6;
    int lane = tid & 63;
    int wid  = blockIdx.x * 4 + wv;
    const int nw = NBLO * 4;
    float sp_acc = 0.f, rg_acc = 0.f;
    for (int b = wid; b < BATCH_; b += nw) {
        int u = users[b], p = pos[b], n = neg[b];
        int ru = u, rp = NU + p, rn = NU + n;
        float uo = ue[(size_t)u * D + lane];
        float po = ie[(size_t)p * D + lane];
        float no = ie[(size_t)n * D + lane];
        float lu = uo + bf2f(o1[(size_t)ru * D + lane]) + bf2f(o2[(size_t)ru * D + lane])
                      + wbuf[(size_t)(0 * BATCH_ + b) * D + lane];
        float lp = po + bf2f(o1[(size_t)rp * D + lane]) + bf2f(o2[(size_t)rp * D + lane])
                      + wbuf[(size_t)(1 * BATCH_ + b) * D + lane];
        float ln_ = no + bf2f(o1[(size_t)rn * D + lane]) + bf2f(o2[(size_t)rn * D + lane])
                      + wbuf[(size_t)(2 * BATCH_ + b) * D + lane];
        float ps = lu * lp;
        float ns = lu * ln_;
        float rg = uo * uo + po * po + no * no;
        #pragma unroll
        for (int off = 32; off > 0; off >>= 1) {
            ps += __shfl_down(ps, off);
            ns += __shfl_down(ns, off);
            rg += __shfl_down(rg, off);
        }
        if (lane == 0) {
            float diff = (ns - ps) * (1.0f / 16.0f);
            float sp = diff > 0.f ? diff + log1pf(expf(-diff)) : log1pf(expf(diff));
            sp_acc += sp;
            rg_acc += rg;
        }
    }
    if (lane == 0) { ssp[wv] = sp_acc; srg[wv] = rg_acc; }
    __syncthreads();
    if (tid == 0) {
        pbuf[blockIdx.x]        = ssp[0] + ssp[1] + ssp[2] + ssp[3];
        pbuf[NBLO + blockIdx.x] = srg[0] + srg[1] + srg[2] + srg[3];
    }
}

// ---- finalize: reduce 512 partials, emit loss -------------------------------
__global__ void finalize_kernel(const float* __restrict__ pbuf, float* __restrict__ out) {
    __shared__ float s1[NBLO];
    __shared__ float s2[NBLO];
    int t = threadIdx.x;
    s1[t] = pbuf[t];
    s2[t] = pbuf[NBLO + t];
    __syncthreads();
    for (int off = NBLO / 2; off > 0; off >>= 1) {
        if (t < off) { s1[t] += s1[t + off]; s2[t] += s2[t + off]; }
        __syncthreads();
    }
    if (t == 0)
        out[0] = s1[0] / (float)BATCH_ + WDECAY * 0.5f * s2[0] / (float)BATCH_;
}

extern "C" void kernel_launch(void* const* d_in, const int* in_sizes, int n_in,
                              void* d_out, int out_size, void* d_ws, size_t ws_size,
                              hipStream_t stream) {
    const float* user_emb = (const float*)d_in[0];
    const float* item_emb = (const float*)d_in[1];
    const int*   g_rows   = (const int*)d_in[2];
    const int*   g_cols   = (const int*)d_in[3];
    const float* g_vals   = (const float*)d_in[4];
    const int*   users    = (const int*)d_in[5];
    const int*   pos      = (const int*)d_in[6];
    const int*   neg      = (const int*)d_in[7];
    float* out = (float*)d_out;

    const size_t TABH = (size_t)NT * D * 2;            // 19.2 MB bf16 table
    char* ws = (char*)d_ws;
    ushort* cur0   = (ushort*)(ws);
    ushort* o1     = (ushort*)(ws + TABH);
    ushort* o2     = (ushort*)(ws + 2 * TABH);
    int2*   colval = (int2*)  (ws + 3 * TABH);                       // 32 MB
    int2*   binned = (int2*)  (ws + 3 * TABH + (size_t)NNZ_ * 8);    // 33.9 MB
    char*   p      = ws + 3 * TABH + (size_t)NNZ_ * 8 + (size_t)NBKT * BCAP * 8;
    int*    rowptr = (int*)(p);      p += ((size_t)(NT + 1) * 4 + 255) / 256 * 256;
    int*    cursor = (int*)(p);      p += (size_t)NBKT * CURS * 4;
    int*    bbase  = (int*)(p);      p += 1024;
    float*  pbuf   = (float*)(p);    p += 2 * NBLO * 4;
    float*  wbuf   = (float*)(p);    // 3*BATCH_*64*4 = 3.1 MB

    hipMemsetAsync(cursor, 0, (size_t)NBKT * CURS * 4, stream);
    init_kernel<<<(NT * D / 4 + 255) / 256, 256, 0, stream>>>(user_emb, item_emb, cur0);

    binA_kernel<<<NBLK_A, 256, 0, stream>>>(g_rows, g_cols, g_vals, cursor, binned);
    bscan_kernel<<<1, 128, 0, stream>>>(cursor, bbase, rowptr);
    binB_kernel<<<NBKT, 1024, 0, stream>>>(binned, cursor, bbase, colval, rowptr);

    const int SPMM_BLOCKS = (NT + 3) / 4;   // one wave per row, 4 waves/block
    spmm_kernel<<<SPMM_BLOCKS, 256, 0, stream>>>(rowptr, colval, cur0, o1);
    spmm_kernel<<<SPMM_BLOCKS, 256, 0, stream>>>(rowptr, colval, o1, o2);

    walk_kernel<<<(3 * BATCH_ + 3) / 4, 256, 0, stream>>>(o2, rowptr, colval,
                                                          users, pos, neg, wbuf);
    loss_kernel<<<NBLO, 256, 0, stream>>>(user_emb, item_emb, o1, o2, wbuf,
                                          users, pos, neg, pbuf);
    finalize_kernel<<<1, NBLO, 0, stream>>>(pbuf, out);
}